// Round 14
// baseline (1976.145 us; speedup 1.0000x reference)
//
#include <hip/hip_runtime.h>
#include <stdint.h>

#define T_STEPS 784
#define H 256
#define NBLK 512        // 1 sample per block, 2 blocks/CU
#define NTHR 256        // 4 waves; wave w owns neurons AND rows [64w, 64w+64)

typedef unsigned long long u64;
typedef unsigned int u32;

// Per-neuron mask parameters, replicating numpy linspace/ceil/round in float64.
__device__ __forceinline__ void mask_params(int j, int& c, int& on, int& ps) {
    const double stepc = (8.0 - 4.0) / 255.0;
    const double stepd = (0.9 - 0.1) / 255.0;
    const double stepp = 4.0 / 255.0;
    double cyc = (j == 255) ? 8.0 : __dadd_rn(__dmul_rn((double)j, stepc), 4.0);
    c = (int)ceil(cyc);
    double dc  = (j == 255) ? 0.9 : __dadd_rn(__dmul_rn((double)j, stepd), 0.1);
    on = (int)ceil(__dmul_rn(dc, (double)c));
    double psd = (j == 255) ? 4.0 : __dmul_rn((double)j, stepp);
    ps = (int)rint(psd);
}

__device__ __forceinline__ void acc_add(const float4& w, float4& a) {
    a.x += w.x; a.y += w.y; a.z += w.z; a.w += w.w;
}

// Paired sparse accumulate: one gate mask drives TWO matrices (same k rows).
// offX/offY: per-lane byte offsets (lane*16 when the lane's 4 output columns
// are alive at the consuming time, else 0 -> all dead lanes share one line).
// Straight-line 16-load batches; binary tail.
__device__ __forceinline__ void consume_pair(const char* __restrict__ bX,
                                             const char* __restrict__ bY,
                                             u64 m, int offX, int offY,
                                             float4& aX, float4& aY) {
    int n = __popcll(m);
    while (n >= 8) {
        int k0=__builtin_ctzll(m); m&=m-1; int k1=__builtin_ctzll(m); m&=m-1;
        int k2=__builtin_ctzll(m); m&=m-1; int k3=__builtin_ctzll(m); m&=m-1;
        int k4=__builtin_ctzll(m); m&=m-1; int k5=__builtin_ctzll(m); m&=m-1;
        int k6=__builtin_ctzll(m); m&=m-1; int k7=__builtin_ctzll(m); m&=m-1;
        float4 x0 = *(const float4*)(bX + (k0<<10) + offX);
        float4 x1 = *(const float4*)(bX + (k1<<10) + offX);
        float4 x2 = *(const float4*)(bX + (k2<<10) + offX);
        float4 x3 = *(const float4*)(bX + (k3<<10) + offX);
        float4 x4 = *(const float4*)(bX + (k4<<10) + offX);
        float4 x5 = *(const float4*)(bX + (k5<<10) + offX);
        float4 x6 = *(const float4*)(bX + (k6<<10) + offX);
        float4 x7 = *(const float4*)(bX + (k7<<10) + offX);
        float4 y0 = *(const float4*)(bY + (k0<<10) + offY);
        float4 y1 = *(const float4*)(bY + (k1<<10) + offY);
        float4 y2 = *(const float4*)(bY + (k2<<10) + offY);
        float4 y3 = *(const float4*)(bY + (k3<<10) + offY);
        float4 y4 = *(const float4*)(bY + (k4<<10) + offY);
        float4 y5 = *(const float4*)(bY + (k5<<10) + offY);
        float4 y6 = *(const float4*)(bY + (k6<<10) + offY);
        float4 y7 = *(const float4*)(bY + (k7<<10) + offY);
        acc_add(x0, aX); acc_add(x1, aX); acc_add(x2, aX); acc_add(x3, aX);
        acc_add(x4, aX); acc_add(x5, aX); acc_add(x6, aX); acc_add(x7, aX);
        acc_add(y0, aY); acc_add(y1, aY); acc_add(y2, aY); acc_add(y3, aY);
        acc_add(y4, aY); acc_add(y5, aY); acc_add(y6, aY); acc_add(y7, aY);
        n -= 8;
    }
    if (n & 4) {
        int k0=__builtin_ctzll(m); m&=m-1; int k1=__builtin_ctzll(m); m&=m-1;
        int k2=__builtin_ctzll(m); m&=m-1; int k3=__builtin_ctzll(m); m&=m-1;
        float4 x0 = *(const float4*)(bX + (k0<<10) + offX);
        float4 x1 = *(const float4*)(bX + (k1<<10) + offX);
        float4 x2 = *(const float4*)(bX + (k2<<10) + offX);
        float4 x3 = *(const float4*)(bX + (k3<<10) + offX);
        float4 y0 = *(const float4*)(bY + (k0<<10) + offY);
        float4 y1 = *(const float4*)(bY + (k1<<10) + offY);
        float4 y2 = *(const float4*)(bY + (k2<<10) + offY);
        float4 y3 = *(const float4*)(bY + (k3<<10) + offY);
        acc_add(x0, aX); acc_add(x1, aX); acc_add(x2, aX); acc_add(x3, aX);
        acc_add(y0, aY); acc_add(y1, aY); acc_add(y2, aY); acc_add(y3, aY);
    }
    if (n & 2) {
        int k0=__builtin_ctzll(m); m&=m-1; int k1=__builtin_ctzll(m); m&=m-1;
        float4 x0 = *(const float4*)(bX + (k0<<10) + offX);
        float4 x1 = *(const float4*)(bX + (k1<<10) + offX);
        float4 y0 = *(const float4*)(bY + (k0<<10) + offY);
        float4 y1 = *(const float4*)(bY + (k1<<10) + offY);
        acc_add(x0, aX); acc_add(x1, aX);
        acc_add(y0, aY); acc_add(y1, aY);
    }
    if (n & 1) {
        int k0 = __builtin_ctzll(m);
        float4 x0 = *(const float4*)(bX + (k0<<10) + offX);
        float4 y0 = *(const float4*)(bY + (k0<<10) + offY);
        acc_add(x0, aX); acc_add(y0, aY);
    }
}

__device__ __forceinline__ void upd(float& mem, float& sp, float h, int mbit) {
    float nm = fmaf(mem * 0.5f, (1.0f - sp), h);
    mem = mbit ? nm : mem;
    sp  = (mbit && (mem > 0.5f)) ? 1.0f : 0.0f;
}

// Tiled transpose of the 4 weight matrices into ws: WT[k][j] = W[j][k].
__global__ __launch_bounds__(256)
void prep_transpose(const float* __restrict__ w1, const float* __restrict__ w2a,
                    const float* __restrict__ w2b, const float* __restrict__ w3,
                    float* __restrict__ ws)
{
    __shared__ float tile[64][65];
    const int bid = blockIdx.x;                 // 64 blocks: m(4) x kt(4) x jt(4)
    const int m  = bid >> 4;
    const int kt = (bid >> 2) & 3;
    const int jt = bid & 3;
    const float* src = (m == 0) ? w1 : (m == 1) ? w2a : (m == 2) ? w2b : w3;
    float* dst = ws + (size_t)m * H * H;
    const int tid = threadIdx.x;
    const int c = tid & 63, r4 = tid >> 6;
    #pragma unroll
    for (int rr = 0; rr < 16; rr++) {
        int r = r4 * 16 + rr;
        tile[r][c] = src[(size_t)(jt * 64 + r) * H + kt * 64 + c];
    }
    __syncthreads();
    #pragma unroll
    for (int rr = 0; rr < 16; rr++) {
        int r = r4 * 16 + rr;
        dst[(size_t)(kt * 64 + r) * H + jt * 64 + c] = tile[c][r];
    }
}

// Layer-pipelined (systolic) slots: slot sl computes L1(sl), L2(sl-1), L3(sl-2).
// All gates known at slot start -> TWO paired load loops (bal1: W1+W2a,
// bal2: W2b+W3), ONE barrier per slot. pex double-buffered by slot parity.
// Column gating: per-lane load offset (lane*16 vs 0) from static blk[] table.
__global__ __launch_bounds__(NTHR, 2)
void srnn_kernel(const float* __restrict__ x,
                 const float* __restrict__ w_i2h1, const float* __restrict__ b_i2h1,
                 const float* __restrict__ b_h2h1,
                 const float* __restrict__ b_i2h2, const float* __restrict__ b_h2h2,
                 const float* __restrict__ b_i2h3,
                 const float* __restrict__ w_h2o3, const float* __restrict__ b_h2o3,
                 const float* __restrict__ ws,     // WT1 | WT2a | WT2b | WT3
                 float* __restrict__ out)
{
    const int tid  = threadIdx.x;
    const int lane = tid & 63;
    const int w    = tid >> 6;         // wave id = j-group = row-group
    const int j    = tid;              // this thread's neuron
    const int l16  = lane * 16;        // byte offset into each row (4 cols/lane)
    const int s    = blockIdx.x;       // sample

    // Wave's row-slice base per matrix: rows [64w, 64w+64), 64KB per slice.
    const char* wt1  = (const char*)ws + (0 << 18) + (w << 16);
    const char* wt2a = (const char*)ws + (1 << 18) + (w << 16);
    const char* wt2b = (const char*)ws + (2 << 18) + (w << 16);
    const char* wt3  = (const char*)ws + (3 << 18) + (w << 16);

    __shared__ float xls[T_STEPS];          // 3.1 KB
    __shared__ float pexA[2][4][H];         // double-buffered partials, 8 KB each
    __shared__ float pexB[2][4][H];
    __shared__ float pexC[2][4][H];
    __shared__ u64 blk[T_STEPS];            // per-step active 4-col-block mask, 6.3 KB
    __shared__ float wred[4][10];

    for (int i = tid; i < T_STEPS; i += NTHR)
        xls[i] = x[(size_t)s * T_STEPS + i];

    int mc, mon, mps;
    mask_params(j, mc, mon, mps);
    int ph = (mc - (mps % mc)) % mc;

    // Static per-step block-active table (R8-verified): blk[t] bit b == 1 iff
    // any j in [4b,4b+4) has mask(j,t)=1.
    {
        unsigned short* blk16 = (unsigned short*)blk;
        int p = ph;
        for (int t = 0; t < T_STEPS; t++) {
            u64 m = __ballot(p < mon);
            u64 bb = m | (m >> 1); bb |= (bb >> 2);
            u64 b2 = __ballot(((bb >> ((lane & 15) << 2)) & 1) != 0);
            if (lane == 0) blk16[t * 4 + w] = (unsigned short)b2;
            p++; if (p == mc) p = 0;
        }
    }

    const float bs1 = b_i2h1[j] + b_h2h1[j];
    const float bs2 = b_i2h2[j] + b_h2h2[j];
    const float bs3 = b_i2h3[j];
    const float wi1 = w_i2h1[j];

    float mem1 = 0.f, mem2 = 0.f, mem3 = 0.f;
    float sp1 = 0.f, sp2 = 0.f, sp3 = 0.f;
    u64 bal1 = 0ull, bal2 = 0ull;      // prev-slot spike ballots (register-resident)
    int mb_d1 = 0, mb_d2 = 0;          // mask bits of times slot-1, slot-2
    float cnt = 0.f;                   // sum_t spk3; out = wo·cnt at end (exact)

    __syncthreads();

    for (int sl = 0; sl < T_STEPS + 2; sl++) {
        const int par  = sl & 1;
        const int mbit = (ph < mon) ? 1 : 0;
        const bool runL1 = (sl < T_STEPS);
        const bool runL2 = (sl >= 1) && (sl <= T_STEPS);
        const bool runL3 = (sl >= 2);

        // Per-lane gated offsets for the 3 consuming times (clamped indices;
        // out-of-range slots have empty ballots or discarded results).
        int t1 = (sl < T_STEPS) ? sl : (T_STEPS - 1);
        int t2 = (sl >= 1) ? ((sl - 1 < T_STEPS) ? sl - 1 : T_STEPS - 1) : 0;
        int t3 = (sl >= 2) ? ((sl - 2 < T_STEPS) ? sl - 2 : T_STEPS - 1) : 0;
        u64 b1t = blk[t1], b2t = blk[t2], b3t = blk[t3];
        u32 h1b = (lane < 32) ? (u32)b1t : (u32)(b1t >> 32);
        u32 h2b = (lane < 32) ? (u32)b2t : (u32)(b2t >> 32);
        u32 h3b = (lane < 32) ? (u32)b3t : (u32)(b3t >> 32);
        const int sel1 = ((h1b >> (lane & 31)) & 1) ? l16 : 0;   // W1 -> pexA (time sl)
        const int sel2 = ((h2b >> (lane & 31)) & 1) ? l16 : 0;   // W2a/W2b -> pexB (sl-1)
        const int sel3 = ((h3b >> (lane & 31)) & 1) ? l16 : 0;   // W3 -> pexC (sl-2)

        // ======== paired load region (2 deep-pipelined loops) ========
        float4 accA = {0.f,0.f,0.f,0.f}, accB = {0.f,0.f,0.f,0.f}, accC = {0.f,0.f,0.f,0.f};
        consume_pair(wt1,  wt2a, bal1, sel1, sel2, accA, accB);  // spk1(sl-1) gates W1, W2a
        consume_pair(wt2b, wt3,  bal2, sel2, sel3, accB, accC);  // spk2(sl-2) gates W2b, W3
        if (runL1) ((float4*)pexA[par][w])[lane] = accA;
        if (runL2) ((float4*)pexB[par][w])[lane] = accB;
        if (runL3) ((float4*)pexC[par][w])[lane] = accC;
        __syncthreads();                           // ONE barrier per slot

        // ======== update region: three upds back-to-back ========
        // Gated-off lanes wrote garbage partials, but only into columns whose
        // mask bit is 0 at the consuming time -> upd's mbit select discards
        // them (R8-verified argument).
        if (runL1) {                               // L1 at time sl
            float hs = (pexA[par][0][j] + pexA[par][1][j])
                     + (pexA[par][2][j] + pexA[par][3][j]);
            float h1 = hs + fmaf(xls[sl], wi1, bs1);
            upd(mem1, sp1, h1, mbit);
            bal1 = __ballot(sp1 != 0.0f);
        }
        if (runL2) {                               // L2 at time sl-1
            float hs = (pexB[par][0][j] + pexB[par][1][j])
                     + (pexB[par][2][j] + pexB[par][3][j]);
            upd(mem2, sp2, hs + bs2, mb_d1);
            bal2 = __ballot(sp2 != 0.0f);
        }
        if (runL3) {                               // L3 at time sl-2
            float hs = (pexC[par][0][j] + pexC[par][1][j])
                     + (pexC[par][2][j] + pexC[par][3][j]);
            upd(mem3, sp3, hs + bs3, mb_d2);
            cnt += sp3;
        }
        mb_d2 = mb_d1; mb_d1 = mbit;
        ph++; if (ph == mc) ph = 0;
        // pex write-after-read safety: slot sl+2 rewrites pex?[par] only after
        // BAR(sl+1), which every wave passes only after finishing slot sl's
        // reads — double buffer + 1 barrier/slot is race-free.
    }

    // ---- output: out[s][i] = (sum_j w_h2o3[i][j]*cnt_j)/784 + b[i]
    #pragma unroll
    for (int i = 0; i < 10; i++) {
        float v = cnt * w_h2o3[i * H + j];
        for (int off = 32; off; off >>= 1) v += __shfl_down(v, off, 64);
        if (lane == 0) wred[w][i] = v;
    }
    __syncthreads();
    if (tid < 10) {
        float sum = wred[0][tid] + wred[1][tid] + wred[2][tid] + wred[3][tid];
        out[(size_t)s * 10 + tid] = sum / 784.0f + b_h2o3[tid];
    }
}

extern "C" void kernel_launch(void* const* d_in, const int* in_sizes, int n_in,
                              void* d_out, int out_size, void* d_ws, size_t ws_size,
                              hipStream_t stream) {
    (void)in_sizes; (void)n_in; (void)ws_size; (void)out_size;
    const float* x      = (const float*)d_in[0];
    const float* w_i2h1 = (const float*)d_in[1];
    const float* b_i2h1 = (const float*)d_in[2];
    const float* w_h2h1 = (const float*)d_in[3];
    const float* b_h2h1 = (const float*)d_in[4];
    const float* w_i2h2 = (const float*)d_in[5];
    const float* b_i2h2 = (const float*)d_in[6];
    const float* w_h2h2 = (const float*)d_in[7];
    const float* b_h2h2 = (const float*)d_in[8];
    const float* w_i2h3 = (const float*)d_in[9];
    const float* b_i2h3 = (const float*)d_in[10];
    const float* w_h2o3 = (const float*)d_in[11];
    const float* b_h2o3 = (const float*)d_in[12];
    float* ws = (float*)d_ws;   // 4 * 256 KB = 1 MB

    prep_transpose<<<64, 256, 0, stream>>>(w_h2h1, w_i2h2, w_h2h2, w_i2h3, ws);
    srnn_kernel<<<NBLK, NTHR, 0, stream>>>(x,
        w_i2h1, b_i2h1, b_h2h1,
        b_i2h2, b_h2h2, b_i2h3,
        w_h2o3, b_h2o3, ws,
        (float*)d_out);
}

// Round 15
// 1724.901 us; speedup vs baseline: 1.1457x; 1.1457x over previous
//
#include <hip/hip_runtime.h>
#include <stdint.h>

#define T_STEPS 784
#define H 256
#define NBLK 512        // 1 sample per block, 2 blocks/CU (16 waves/CU)
#define NTHR 512        // 8 waves; wave w owns rows AND neurons [32w, 32w+32)

typedef unsigned long long u64;
typedef unsigned int u32;

// Per-neuron mask parameters, replicating numpy linspace/ceil/round in float64.
__device__ __forceinline__ void mask_params(int j, int& c, int& on, int& ps) {
    const double stepc = (8.0 - 4.0) / 255.0;
    const double stepd = (0.9 - 0.1) / 255.0;
    const double stepp = 4.0 / 255.0;
    double cyc = (j == 255) ? 8.0 : __dadd_rn(__dmul_rn((double)j, stepc), 4.0);
    c = (int)ceil(cyc);
    double dc  = (j == 255) ? 0.9 : __dadd_rn(__dmul_rn((double)j, stepd), 0.1);
    on = (int)ceil(__dmul_rn(dc, (double)c));
    double psd = (j == 255) ? 4.0 : __dmul_rn((double)j, stepp);
    ps = (int)rint(psd);
}

__device__ __forceinline__ void acc_add(const float4& w, float4& a) {
    a.x += w.x; a.y += w.y; a.z += w.z; a.w += w.w;
}

// Paired sparse accumulate: one gate mask drives TWO matrices (same k rows).
// m: low-32-bit row mask (wave's own ballot low half, register-resident).
// Rows 1KB apart; lane covers 4 cols via l16. Straight-line batches (R11/R12
// lesson: no data-dependent branches inside batches); binary tail.
__device__ __forceinline__ void consume_pair(const char* __restrict__ bX,
                                             const char* __restrict__ bY,
                                             u64 m, int l16,
                                             float4& aX, float4& aY) {
    int n = __popcll(m);
    while (n >= 8) {
        int k0=__builtin_ctzll(m); m&=m-1; int k1=__builtin_ctzll(m); m&=m-1;
        int k2=__builtin_ctzll(m); m&=m-1; int k3=__builtin_ctzll(m); m&=m-1;
        int k4=__builtin_ctzll(m); m&=m-1; int k5=__builtin_ctzll(m); m&=m-1;
        int k6=__builtin_ctzll(m); m&=m-1; int k7=__builtin_ctzll(m); m&=m-1;
        float4 x0 = *(const float4*)(bX + (k0<<10) + l16);
        float4 x1 = *(const float4*)(bX + (k1<<10) + l16);
        float4 x2 = *(const float4*)(bX + (k2<<10) + l16);
        float4 x3 = *(const float4*)(bX + (k3<<10) + l16);
        float4 x4 = *(const float4*)(bX + (k4<<10) + l16);
        float4 x5 = *(const float4*)(bX + (k5<<10) + l16);
        float4 x6 = *(const float4*)(bX + (k6<<10) + l16);
        float4 x7 = *(const float4*)(bX + (k7<<10) + l16);
        float4 y0 = *(const float4*)(bY + (k0<<10) + l16);
        float4 y1 = *(const float4*)(bY + (k1<<10) + l16);
        float4 y2 = *(const float4*)(bY + (k2<<10) + l16);
        float4 y3 = *(const float4*)(bY + (k3<<10) + l16);
        float4 y4 = *(const float4*)(bY + (k4<<10) + l16);
        float4 y5 = *(const float4*)(bY + (k5<<10) + l16);
        float4 y6 = *(const float4*)(bY + (k6<<10) + l16);
        float4 y7 = *(const float4*)(bY + (k7<<10) + l16);
        acc_add(x0, aX); acc_add(x1, aX); acc_add(x2, aX); acc_add(x3, aX);
        acc_add(x4, aX); acc_add(x5, aX); acc_add(x6, aX); acc_add(x7, aX);
        acc_add(y0, aY); acc_add(y1, aY); acc_add(y2, aY); acc_add(y3, aY);
        acc_add(y4, aY); acc_add(y5, aY); acc_add(y6, aY); acc_add(y7, aY);
        n -= 8;
    }
    if (n & 4) {
        int k0=__builtin_ctzll(m); m&=m-1; int k1=__builtin_ctzll(m); m&=m-1;
        int k2=__builtin_ctzll(m); m&=m-1; int k3=__builtin_ctzll(m); m&=m-1;
        float4 x0 = *(const float4*)(bX + (k0<<10) + l16);
        float4 x1 = *(const float4*)(bX + (k1<<10) + l16);
        float4 x2 = *(const float4*)(bX + (k2<<10) + l16);
        float4 x3 = *(const float4*)(bX + (k3<<10) + l16);
        float4 y0 = *(const float4*)(bY + (k0<<10) + l16);
        float4 y1 = *(const float4*)(bY + (k1<<10) + l16);
        float4 y2 = *(const float4*)(bY + (k2<<10) + l16);
        float4 y3 = *(const float4*)(bY + (k3<<10) + l16);
        acc_add(x0, aX); acc_add(x1, aX); acc_add(x2, aX); acc_add(x3, aX);
        acc_add(y0, aY); acc_add(y1, aY); acc_add(y2, aY); acc_add(y3, aY);
    }
    if (n & 2) {
        int k0=__builtin_ctzll(m); m&=m-1; int k1=__builtin_ctzll(m); m&=m-1;
        float4 x0 = *(const float4*)(bX + (k0<<10) + l16);
        float4 x1 = *(const float4*)(bX + (k1<<10) + l16);
        float4 y0 = *(const float4*)(bY + (k0<<10) + l16);
        float4 y1 = *(const float4*)(bY + (k1<<10) + l16);
        acc_add(x0, aX); acc_add(x1, aX);
        acc_add(y0, aY); acc_add(y1, aY);
    }
    if (n & 1) {
        int k0 = __builtin_ctzll(m);
        float4 x0 = *(const float4*)(bX + (k0<<10) + l16);
        float4 y0 = *(const float4*)(bY + (k0<<10) + l16);
        acc_add(x0, aX); acc_add(y0, aY);
    }
}

__device__ __forceinline__ void upd(float& mem, float& sp, float h, int mbit) {
    float nm = fmaf(mem * 0.5f, (1.0f - sp), h);
    mem = mbit ? nm : mem;
    sp  = (mbit && (mem > 0.5f)) ? 1.0f : 0.0f;
}

// Tiled transpose of the 4 weight matrices into ws: WT[k][j] = W[j][k].
__global__ __launch_bounds__(256)
void prep_transpose(const float* __restrict__ w1, const float* __restrict__ w2a,
                    const float* __restrict__ w2b, const float* __restrict__ w3,
                    float* __restrict__ ws)
{
    __shared__ float tile[64][65];
    const int bid = blockIdx.x;                 // 64 blocks: m(4) x kt(4) x jt(4)
    const int m  = bid >> 4;
    const int kt = (bid >> 2) & 3;
    const int jt = bid & 3;
    const float* src = (m == 0) ? w1 : (m == 1) ? w2a : (m == 2) ? w2b : w3;
    float* dst = ws + (size_t)m * H * H;
    const int tid = threadIdx.x;
    const int c = tid & 63, r4 = tid >> 6;
    #pragma unroll
    for (int rr = 0; rr < 16; rr++) {
        int r = r4 * 16 + rr;
        tile[r][c] = src[(size_t)(jt * 64 + r) * H + kt * 64 + c];
    }
    __syncthreads();
    #pragma unroll
    for (int rr = 0; rr < 16; rr++) {
        int r = r4 * 16 + rr;
        dst[(size_t)(kt * 64 + r) * H + jt * 64 + c] = tile[c][r];
    }
}

// Layer-pipelined (systolic) slots: slot sl computes L1(sl), L2(sl-1), L3(sl-2).
// 8 waves; wave w owns rows AND neurons [32w,32w+32): lanes 0-31 = neurons,
// lanes 32-63 duplicate them (identical upds) so the wave's own ballot low-u32
// is its register-resident row gate. One barrier per slot; pex double-buffered.
__global__ __launch_bounds__(NTHR, 4)
void srnn_kernel(const float* __restrict__ x,
                 const float* __restrict__ w_i2h1, const float* __restrict__ b_i2h1,
                 const float* __restrict__ b_h2h1,
                 const float* __restrict__ b_i2h2, const float* __restrict__ b_h2h2,
                 const float* __restrict__ b_i2h3,
                 const float* __restrict__ w_h2o3, const float* __restrict__ b_h2o3,
                 const float* __restrict__ ws,     // WT1 | WT2a | WT2b | WT3
                 float* __restrict__ out)
{
    const int tid  = threadIdx.x;
    const int lane = tid & 63;
    const int w    = tid >> 6;         // wave id = 32-row group = 32-neuron group
    const int j    = w * 32 + (lane & 31);  // this thread's neuron (duplicated)
    const int l16  = lane * 16;        // byte offset into each row (4 cols/lane)
    const int s    = blockIdx.x;       // sample

    // Wave's row-slice base per matrix: rows [32w, 32w+32), 32KB per slice.
    const char* wt1  = (const char*)ws + (0 << 18) + (w << 15);
    const char* wt2a = (const char*)ws + (1 << 18) + (w << 15);
    const char* wt2b = (const char*)ws + (2 << 18) + (w << 15);
    const char* wt3  = (const char*)ws + (3 << 18) + (w << 15);

    __shared__ float xls[T_STEPS];          // 3.1 KB
    __shared__ float pexA[2][8][H];         // double-buffered partials, 16 KB each
    __shared__ float pexB[2][8][H];
    __shared__ float pexC[2][8][H];
    __shared__ float wred[8][10];

    for (int i = tid; i < T_STEPS; i += NTHR)
        xls[i] = x[(size_t)s * T_STEPS + i];

    int mc, mon, mps;
    mask_params(j, mc, mon, mps);
    int ph = (mc - (mps % mc)) % mc;

    const float bs1 = b_i2h1[j] + b_h2h1[j];
    const float bs2 = b_i2h2[j] + b_h2h2[j];
    const float bs3 = b_i2h3[j];
    const float wi1 = w_i2h1[j];

    float mem1 = 0.f, mem2 = 0.f, mem3 = 0.f;
    float sp1 = 0.f, sp2 = 0.f, sp3 = 0.f;
    u64 bal1 = 0ull, bal2 = 0ull;      // prev-slot spike ballots (low-32 = row gate)
    int mb_d1 = 0, mb_d2 = 0;          // mask bits of times slot-1, slot-2
    float cnt = 0.f;                   // sum_t spk3; out = wo·cnt at end (exact)

    __syncthreads();

    for (int sl = 0; sl < T_STEPS + 2; sl++) {
        const int par  = sl & 1;
        const int mbit = (ph < mon) ? 1 : 0;
        const bool runL1 = (sl < T_STEPS);
        const bool runL2 = (sl >= 1) && (sl <= T_STEPS);
        const bool runL3 = (sl >= 2);

        // ======== paired load region (register-resident u32 gates) ========
        float4 accA = {0.f,0.f,0.f,0.f}, accB = {0.f,0.f,0.f,0.f}, accC = {0.f,0.f,0.f,0.f};
        consume_pair(wt1,  wt2a, bal1 & 0xFFFFFFFFull, l16, accA, accB);
        consume_pair(wt2b, wt3,  bal2 & 0xFFFFFFFFull, l16, accB, accC);
        if (runL1) ((float4*)pexA[par][w])[lane] = accA;
        if (runL2) ((float4*)pexB[par][w])[lane] = accB;
        if (runL3) ((float4*)pexC[par][w])[lane] = accC;
        __syncthreads();                           // ONE barrier per slot

        // ======== update region: three upds back-to-back (lane-duplicated) ====
        if (runL1) {                               // L1 at time sl
            float hs = ((pexA[par][0][j] + pexA[par][1][j])
                      + (pexA[par][2][j] + pexA[par][3][j]))
                     + ((pexA[par][4][j] + pexA[par][5][j])
                      + (pexA[par][6][j] + pexA[par][7][j]));
            float h1 = hs + fmaf(xls[sl], wi1, bs1);
            upd(mem1, sp1, h1, mbit);
            bal1 = __ballot(sp1 != 0.0f);
        }
        if (runL2) {                               // L2 at time sl-1
            float hs = ((pexB[par][0][j] + pexB[par][1][j])
                      + (pexB[par][2][j] + pexB[par][3][j]))
                     + ((pexB[par][4][j] + pexB[par][5][j])
                      + (pexB[par][6][j] + pexB[par][7][j]));
            upd(mem2, sp2, hs + bs2, mb_d1);
            bal2 = __ballot(sp2 != 0.0f);
        }
        if (runL3) {                               // L3 at time sl-2
            float hs = ((pexC[par][0][j] + pexC[par][1][j])
                      + (pexC[par][2][j] + pexC[par][3][j]))
                     + ((pexC[par][4][j] + pexC[par][5][j])
                      + (pexC[par][6][j] + pexC[par][7][j]));
            upd(mem3, sp3, hs + bs3, mb_d2);
            cnt += sp3;
        }
        mb_d2 = mb_d1; mb_d1 = mbit;
        ph++; if (ph == mc) ph = 0;
        // pex write-after-read safety: slot sl+2 rewrites pex?[par] only after
        // BAR(sl+1); every wave reads pex?[par] in U(sl) before reaching
        // BAR(sl+1) — double buffer + 1 barrier/slot is race-free (R12 arg).
    }

    // ---- output: out[s][i] = (sum_j w_h2o3[i][j]*cnt_j)/784 + b[i]
    // Lanes 32-63 hold duplicated neurons: reduce over lanes 0-31 only.
    float wo_i;
    #pragma unroll
    for (int i = 0; i < 10; i++) {
        wo_i = w_h2o3[i * H + j];
        float v = cnt * wo_i;
        for (int off = 16; off; off >>= 1) v += __shfl_down(v, off, 32);
        if (lane == 0) wred[w][i] = v;
    }
    __syncthreads();
    if (tid < 10) {
        float sum = ((wred[0][tid] + wred[1][tid]) + (wred[2][tid] + wred[3][tid]))
                  + ((wred[4][tid] + wred[5][tid]) + (wred[6][tid] + wred[7][tid]));
        out[(size_t)s * 10 + tid] = sum / 784.0f + b_h2o3[tid];
    }
}

extern "C" void kernel_launch(void* const* d_in, const int* in_sizes, int n_in,
                              void* d_out, int out_size, void* d_ws, size_t ws_size,
                              hipStream_t stream) {
    (void)in_sizes; (void)n_in; (void)ws_size; (void)out_size;
    const float* x      = (const float*)d_in[0];
    const float* w_i2h1 = (const float*)d_in[1];
    const float* b_i2h1 = (const float*)d_in[2];
    const float* w_h2h1 = (const float*)d_in[3];
    const float* b_h2h1 = (const float*)d_in[4];
    const float* w_i2h2 = (const float*)d_in[5];
    const float* b_i2h2 = (const float*)d_in[6];
    const float* w_h2h2 = (const float*)d_in[7];
    const float* b_h2h2 = (const float*)d_in[8];
    const float* w_i2h3 = (const float*)d_in[9];
    const float* b_i2h3 = (const float*)d_in[10];
    const float* w_h2o3 = (const float*)d_in[11];
    const float* b_h2o3 = (const float*)d_in[12];
    float* ws = (float*)d_ws;   // 4 * 256 KB = 1 MB

    prep_transpose<<<64, 256, 0, stream>>>(w_h2h1, w_i2h2, w_h2h2, w_i2h3, ws);
    srnn_kernel<<<NBLK, NTHR, 0, stream>>>(x,
        w_i2h1, b_i2h1, b_h2h1,
        b_i2h2, b_h2h2, b_i2h3,
        w_h2o3, b_h2o3, ws,
        (float*)d_out);
}